// Round 20
// baseline (201.799 us; speedup 1.0000x reference)
//
#include <hip/hip_runtime.h>
#include <cstddef>
#include <cstdint>

// ---------------- problem constants ----------------
constexpr int L_IN   = 16384;
constexpr int L_SEQ  = 2047;          // (16384-16)/8 + 1
constexpr int BATCH  = 8;
constexpr int M_TOK  = BATCH * L_SEQ; // 16376
constexpr int D_INNER = 512;
constexpr int NHEADS  = 8;
constexpr int HEADDIM = 64;
constexpr int D_STATE = 128;
constexpr int CONV_DIM = 768;
constexpr int D_IN_PROJ = 1288;

// SSD chunking
constexpr int QC  = 64;
constexpr int NCH = 32;

// padded stride for transposed LDS tiles
constexpr int TP = 84;

// ---------------- workspace layout (float slots) ----------------
constexpr size_t OFF_U    = 0;                       // ub bf16 / later Yg bf16
constexpr size_t OFF_PB   = OFF_U   + 2096128;       // im2col bf16
constexpr size_t OFF_ZB   = OFF_U   + 4192256;       // z bf16 [row][512]
constexpr size_t OFF_XBC  = OFF_ZB  + 4192256;       // xBC bf16 [row][768]
constexpr size_t OFF_DT   = OFF_XBC + 6288384;       // dt fp32 [row][8]
constexpr size_t OFF_AW   = OFF_DT  + 131008;        // aw fp32
constexpr size_t OFF_XC   = OFF_AW  + 131008;        // xc bf16 [row][768]
constexpr size_t OFF_Y    = OFF_XC  + 6288384;       // v bf16 [row][512] (gated)
constexpr size_t OFF_SCL  = OFF_Y   + 4192256;       // scale fp32 [16376] (in old YC1)
constexpr size_t OFF_PBUF = OFF_SCL + 131008;        // Pbuf fp32
constexpr size_t OFF_HS   = OFF_PBUF + 2048;         // HS bf16
constexpr size_t OFF_WBIN = OFF_HS  + 8388608;
constexpr size_t OFF_WBF  = OFF_WBIN + 164864;
constexpr size_t OFF_W2   = OFF_WBF + 8192;
// OOB-read audit: y16 over-reads rows 16376..16383 land in scale region
// (finite fp32) — store-guarded. Others unchanged from R10.

using short8 = __attribute__((ext_vector_type(8))) short;  // 8 bf16
using short4v = __attribute__((ext_vector_type(4))) short;
using f32x4  = __attribute__((ext_vector_type(4))) float;
typedef unsigned short ushort_t;

__device__ __forceinline__ ushort_t f2bf(float f) {        // RNE f32->bf16
  uint32_t u = __float_as_uint(f);
  u += 0x7fffu + ((u >> 16) & 1u);
  return (ushort_t)(u >> 16);
}
__device__ __forceinline__ float bf2f(ushort_t h) {
  return __uint_as_float(((uint32_t)h) << 16);
}
__device__ __forceinline__ float siluf(float a) { return a / (1.f + expf(-a)); }
__device__ __forceinline__ short8 ld8(const short* p) {
  short4v a = *(const short4v*)p;
  short4v b = *(const short4v*)(p + 4);
  short8 r;
  r[0] = a[0]; r[1] = a[1]; r[2] = a[2]; r[3] = a[3];
  r[4] = b[0]; r[5] = b[1]; r[6] = b[2]; r[7] = b[3];
  return r;
}
#define MFMA16(a, b, c) __builtin_amdgcn_mfma_f32_16x16x32_bf16(a, b, c, 0, 0, 0)

#define GLD_LDS(gp, lp) __builtin_amdgcn_global_load_lds( \
    (const __attribute__((address_space(1))) void*)(gp),  \
    (__attribute__((address_space(3))) void*)(lp), 16, 0, 0)

// ============================================================
// K_prep: merged {im2col | weight casts | W2 combine (x norm_w fold)}
// ============================================================
__global__ __launch_bounds__(256) void k_prep(const float* __restrict__ x,
    const float* __restrict__ w1, const float* __restrict__ w3,
    const float* __restrict__ conv1_w, const float* __restrict__ wout,
    const float* __restrict__ norm_w,
    ushort_t* __restrict__ PB, ushort_t* __restrict__ o1, ushort_t* __restrict__ o3,
    ushort_t* __restrict__ W2b) {
  const int bid = blockIdx.x;
  const int tid = threadIdx.x;
  if (bid < 512) {
    int idx = bid * 256 + tid;
    if (idx >= M_TOK * 8) return;
    int oct = idx & 7, row = idx >> 3;
    int t = row % L_SEQ, b = row / L_SEQ;
    int ic = oct >> 1, k0 = (oct & 1) * 8;
    const float* src = x + ((size_t)b * 4 + ic) * L_IN + t * 8 + k0;
    float4 a0 = *(const float4*)src;
    float4 a1 = *(const float4*)(src + 4);
    short8 o;
    o[0] = (short)f2bf(a0.x); o[1] = (short)f2bf(a0.y);
    o[2] = (short)f2bf(a0.z); o[3] = (short)f2bf(a0.w);
    o[4] = (short)f2bf(a1.x); o[5] = (short)f2bf(a1.y);
    o[6] = (short)f2bf(a1.z); o[7] = (short)f2bf(a1.w);
    *(short8*)(PB + (size_t)row * 64 + oct * 8) = o;
  } else if (bid < 1800) {
    int i = (bid - 512) * 256 + tid;
    if (i < D_IN_PROJ * 256) o1[i] = f2bf(w1[i]);
    if (i < 256 * 64)        o3[i] = f2bf(w3[i]);
  } else {
    const int r = bid - 1800;          // 0..127
    const int oc = r >> 4, k = r & 15;
    const int d0 = tid;
    float acc0 = 0.f, acc1 = 0.f;
    for (int o = 0; o < 256; o++) {
      float wv = conv1_w[((size_t)oc * 256 + o) * 16 + k];
      acc0 = fmaf(wv, wout[(size_t)o * 512 + d0], acc0);
      acc1 = fmaf(wv, wout[(size_t)o * 512 + d0 + 256], acc1);
    }
    // fold norm_w into the K dimension (scale applied in W2-GEMM epilogue)
    W2b[(size_t)r * 512 + d0]       = f2bf(acc0 * norm_w[d0]);
    W2b[(size_t)r * 512 + d0 + 256] = f2bf(acc1 * norm_w[d0 + 256]);
  }
}

// ============================================================
// K2: bf16 MFMA GEMM NT — 2-phase dbuf global_load_lds staging.
// EPI=1: +bias+relu bf16 store.  EPI=2: in_proj region-split.
// EPI=3: bf16 packed-pair store x row-scale (bias arg = scale[gm]).
// ============================================================
template<int EPI>
__global__ __launch_bounds__(256) void gemm_bf16(const ushort_t* __restrict__ A, int lda,
    const ushort_t* __restrict__ B, int ldb, float* __restrict__ C,
    const float* __restrict__ bias, int M, int N, int K, int nx,
    ushort_t* __restrict__ zb, ushort_t* __restrict__ xbcb,
    float* __restrict__ dtb, float* __restrict__ awb,
    const float* __restrict__ dt_bias, const float* __restrict__ A_log) {
  __shared__ __attribute__((aligned(16))) ushort_t sA[2][128 * 64];
  __shared__ __attribute__((aligned(16))) ushort_t sB[2][128 * 64];
  const int tid = threadIdx.x;
  const int cpx = gridDim.x >> 3;
  const int swz = (blockIdx.x & 7) * cpx + (blockIdx.x >> 3);
  const int m0 = (swz / nx) * 128, n0 = (swz % nx) * 128;
  const int w = tid >> 6, lane = tid & 63;
  const int l15 = lane & 15, lK = lane >> 4;
  const int wr = w >> 1, wc = w & 1;
  f32x4 acc[4][4] = {};

  auto STAGE = [&](int buf, int k0) {
#pragma unroll
    for (int j = 0; j < 4; j++) {
      int idx = j * 256 + tid;
      int r = idx >> 3;
      int ss = (idx & 7) ^ (r & 7);
      GLD_LDS(A + (size_t)(m0 + r) * lda + k0 + ss * 8, &sA[buf][(j * 256 + w * 64) * 8]);
      GLD_LDS(B + (size_t)(n0 + r) * ldb + k0 + ss * 8, &sB[buf][(j * 256 + w * 64) * 8]);
    }
  };

  STAGE(0, 0);
  __syncthreads();
  int cur = 0;
  for (int k0 = 0; k0 < K; k0 += 64) {
    if (k0 + 64 < K) STAGE(cur ^ 1, k0 + 64);
#pragma unroll
    for (int kk = 0; kk < 2; kk++) {
      short8 af[4], bf[4];
#pragma unroll
      for (int mt = 0; mt < 4; mt++) {
        int r = wr * 64 + mt * 16 + l15;
        af[mt] = *(const short8*)&sA[cur][r * 64 + (((kk * 4 + lK) ^ (r & 7)) * 8)];
      }
#pragma unroll
      for (int nt = 0; nt < 4; nt++) {
        int r = wc * 64 + nt * 16 + l15;
        bf[nt] = *(const short8*)&sB[cur][r * 64 + (((kk * 4 + lK) ^ (r & 7)) * 8)];
      }
#pragma unroll
      for (int mt = 0; mt < 4; mt++)
#pragma unroll
        for (int nt = 0; nt < 4; nt++)
          acc[mt][nt] = MFMA16(af[mt], bf[nt], acc[mt][nt]);
    }
    __syncthreads();
    cur ^= 1;
  }
  if constexpr (EPI == 1) {
    ushort_t* Cb = (ushort_t*)C;
#pragma unroll
    for (int mt = 0; mt < 4; mt++)
#pragma unroll
      for (int i = 0; i < 4; i++) {
        int gm = m0 + wr * 64 + mt * 16 + lK * 4 + i;
#pragma unroll
        for (int nt = 0; nt < 4; nt++) {
          int gn = n0 + wc * 64 + nt * 16 + l15;
          float v = fmaxf(acc[mt][nt][i] + bias[gn], 0.f);
          uint32_t mine = f2bf(v);
          uint32_t other = (uint32_t)__shfl_xor((int)mine, 1, 64);
          if (((lane & 1) == 0) && gm < M)
            *(uint32_t*)(Cb + (size_t)gm * N + gn) = mine | (other << 16);
        }
      }
  } else if constexpr (EPI == 3) {
    ushort_t* Cb = (ushort_t*)C;
#pragma unroll
    for (int mt = 0; mt < 4; mt++)
#pragma unroll
      for (int i = 0; i < 4; i++) {
        int gm = m0 + wr * 64 + mt * 16 + lK * 4 + i;
        float sc = (gm < M) ? bias[gm] : 0.f;    // per-row RMSNorm scale
#pragma unroll
        for (int nt = 0; nt < 4; nt++) {
          int gn = n0 + wc * 64 + nt * 16 + l15;
          uint32_t mine = f2bf(acc[mt][nt][i] * sc);
          uint32_t other = (uint32_t)__shfl_xor((int)mine, 1, 64);
          if (((lane & 1) == 0) && gm < M)
            *(uint32_t*)(Cb + (size_t)gm * N + gn) = mine | (other << 16);
        }
      }
  } else {
    if (n0 < 1280) {
      ushort_t* dst = (n0 < 512) ? zb : xbcb;
      const int ldd  = (n0 < 512) ? 512 : 768;
      const int coff = (n0 < 512) ? 0 : 512;
#pragma unroll
      for (int mt = 0; mt < 4; mt++)
#pragma unroll
        for (int i = 0; i < 4; i++) {
          int gm = m0 + wr * 64 + mt * 16 + lK * 4 + i;
#pragma unroll
          for (int nt = 0; nt < 4; nt++) {
            int gn = n0 + wc * 64 + nt * 16 + l15;
            uint32_t mine = f2bf(acc[mt][nt][i]);
            uint32_t other = (uint32_t)__shfl_xor((int)mine, 1, 64);
            if (((lane & 1) == 0) && gm < M)
              *(uint32_t*)(dst + (size_t)gm * ldd + (gn - coff)) = mine | (other << 16);
          }
        }
    } else {
#pragma unroll
      for (int mt = 0; mt < 4; mt++)
#pragma unroll
        for (int i = 0; i < 4; i++) {
          int gm = m0 + wr * 64 + mt * 16 + lK * 4 + i;
          if (gm >= M) continue;
#pragma unroll
          for (int nt = 0; nt < 4; nt++) {
            int gn = n0 + wc * 64 + nt * 16 + l15;
            if (gn < N) {
              int hd = gn - 1280;
              float v = acc[mt][nt][i] + dt_bias[hd];
              float sp = (v > 20.f) ? v : log1pf(expf(v));
              dtb[(size_t)gm * 8 + hd] = sp;
              awb[(size_t)gm * 8 + hd] = -expf(A_log[hd]) * sp;
            }
          }
        }
    }
  }
}

// ============================================================
// K4: depthwise causal conv + bias + silu, t-blocked sliding window.
// ============================================================
__global__ __launch_bounds__(192) void k_dw(const ushort_t* __restrict__ xbcb,
    const float* __restrict__ w, const float* __restrict__ bias,
    ushort_t* __restrict__ xcb) {
  const int bid = blockIdx.x;          // b*512 + tb
  const int tb = bid & 511, b = bid >> 9;
  const int t0 = tb * 4;
  const int c = threadIdx.x * 4;
  const size_t rowb = (size_t)b * L_SEQ;
  float wr[4][4];
#pragma unroll
  for (int j = 0; j < 4; j++)
#pragma unroll
    for (int k = 0; k < 4; k++) wr[j][k] = w[(c + j) * 4 + k];
  const float4 bs = {bias[c], bias[c + 1], bias[c + 2], bias[c + 3]};
  float v[7][4];
#pragma unroll
  for (int r = 0; r < 7; r++) {
    int tt = t0 - 3 + r;
    if (tt >= 0 && tt < L_SEQ) {
      uint2 pk = *(const uint2*)(xbcb + (rowb + tt) * CONV_DIM + c);
      v[r][0] = bf2f((ushort_t)(pk.x & 0xffff));
      v[r][1] = bf2f((ushort_t)(pk.x >> 16));
      v[r][2] = bf2f((ushort_t)(pk.y & 0xffff));
      v[r][3] = bf2f((ushort_t)(pk.y >> 16));
    } else {
      v[r][0] = v[r][1] = v[r][2] = v[r][3] = 0.f;
    }
  }
#pragma unroll
  for (int o = 0; o < 4; o++) {
    int t = t0 + o;
    if (t >= L_SEQ) break;
    float a0 = bs.x, a1 = bs.y, a2 = bs.z, a3 = bs.w;
#pragma unroll
    for (int k = 0; k < 4; k++) {
      a0 = fmaf(v[o + k][0], wr[0][k], a0);
      a1 = fmaf(v[o + k][1], wr[1][k], a1);
      a2 = fmaf(v[o + k][2], wr[2][k], a2);
      a3 = fmaf(v[o + k][3], wr[3][k], a3);
    }
    uint2 ov;
    ov.x = (uint32_t)f2bf(siluf(a0)) | ((uint32_t)f2bf(siluf(a1)) << 16);
    ov.y = (uint32_t)f2bf(siluf(a2)) | ((uint32_t)f2bf(siluf(a3)) << 16);
    *(uint2*)(xcb + (rowb + t) * CONV_DIM + c) = ov;
  }
}

// ============================================================
// K5a: SSD chunk states (TP-padded transpose tiles; chunked XCD swizzle)
// ============================================================
__global__ __launch_bounds__(256) void k_ssd_state(const ushort_t* __restrict__ xcb,
    const float* __restrict__ dtb, const float* __restrict__ aw,
    ushort_t* __restrict__ HSb, float* __restrict__ Pbuf) {
  const int L = (blockIdx.x & 7) * 256 + (blockIdx.x >> 3);
  const int ch = L & 31, bh = L >> 5;
  const int b = bh >> 3, h = bh & 7;
  const int t0 = ch * QC;
  const int valid = (L_SEQ - t0 < QC) ? (L_SEQ - t0) : QC;
  const size_t rowbase = (size_t)b * L_SEQ;
  __shared__ __attribute__((aligned(16))) short sBT[128][TP];
  __shared__ __attribute__((aligned(16))) short sXw[64][TP];
  __shared__ float sW[64];
  __shared__ float sLtot;
  const int tid = threadIdx.x;
  if (tid < 64) {
    float aa = 0.f, dd = 0.f;
    if (tid < valid) { size_t r8 = (rowbase + t0 + tid) * 8 + h; aa = aw[r8]; dd = dtb[r8]; }
    float s = aa;
#pragma unroll
    for (int d = 1; d < 64; d <<= 1) { float o = __shfl_up(s, d, 64); if (tid >= d) s += o; }
    float Lt = __shfl(s, 63, 64);
    sW[tid] = expf(Lt - s) * dd;
    if (tid == 63) sLtot = s;
  }
  __syncthreads();
  for (int i = tid; i < 64 * 16; i += 256) {
    int r = i >> 4, q = (i & 15) * 8;
    short8 v = {0, 0, 0, 0, 0, 0, 0, 0};
    if (r < valid) v = *(const short8*)(xcb + (rowbase + t0 + r) * CONV_DIM + 512 + q);
#pragma unroll
    for (int j = 0; j < 8; j++) sBT[q + j][r] = v[j];
  }
  for (int i = tid; i < 64 * 8; i += 256) {
    int r = i >> 3, q = (i & 7) * 8;
    short8 v = {0, 0, 0, 0, 0, 0, 0, 0};
    if (r < valid) v = *(const short8*)(xcb + (rowbase + t0 + r) * CONV_DIM + h * 64 + q);
    float wv = sW[r];
#pragma unroll
    for (int j = 0; j < 8; j++) sXw[q + j][r] = (short)f2bf(bf2f((ushort_t)v[j]) * wv);
  }
  __syncthreads();
  const int w = tid >> 6, l15 = tid & 15, lK = (tid & 63) >> 4;
  f32x4 acc[2][4] = {};
  short8 afr[2][2];
#pragma unroll
  for (int j = 0; j < 2; j++)
#pragma unroll
    for (int kt = 0; kt < 2; kt++)
      afr[j][kt] = ld8(&sBT[(w * 2 + j) * 16 + l15][kt * 32 + lK * 8]);
#pragma unroll
  for (int pt = 0; pt < 4; pt++) {
#pragma unroll
    for (int kt = 0; kt < 2; kt++) {
      short8 bfr = ld8(&sXw[pt * 16 + l15][kt * 32 + lK * 8]);
      acc[0][pt] = MFMA16(afr[0][kt], bfr, acc[0][pt]);
      acc[1][pt] = MFMA16(afr[1][kt], bfr, acc[1][pt]);
    }
  }
  ushort_t* dst = HSb + ((size_t)bh * NCH + ch) * 8192;
#pragma unroll
  for (int j = 0; j < 2; j++)
#pragma unroll
    for (int pt = 0; pt < 4; pt++)
#pragma unroll
      for (int i = 0; i < 4; i++) {
        int n = (w * 2 + j) * 16 + lK * 4 + i, p = pt * 16 + l15;
        uint32_t mine = f2bf(acc[j][pt][i]);
        uint32_t other = (uint32_t)__shfl_xor((int)mine, 1, 64);
        if ((l15 & 1) == 0)
          *(uint32_t*)(dst + n * 64 + p) = mine | (other << 16);
      }
  if (tid == 0) Pbuf[bh * NCH + ch] = expf(sLtot);
}

// ============================================================
// K5b: inter-chunk combine (batch reg load, fp32 chain, batch store)
// ============================================================
__global__ __launch_bounds__(256) void k_ssd_comb(ushort_t* __restrict__ HSb,
                                                  const float* __restrict__ Pbuf) {
  const int bh = blockIdx.y;
  const int e2 = blockIdx.x * 256 + threadIdx.x;
  const size_t base = (size_t)bh * NCH * 8192 + (size_t)e2 * 2;
  uint32_t pk[NCH];
  float P[NCH];
#pragma unroll
  for (int c = 0; c < NCH; c++) pk[c] = *(const uint32_t*)(HSb + base + (size_t)c * 8192);
#pragma unroll
  for (int c = 0; c < NCH; c++) P[c] = Pbuf[bh * NCH + c];
  float run0 = 0.f, run1 = 0.f;
#pragma unroll
  for (int c = 0; c < NCH; c++) {
    run0 = fmaf(P[c], run0, bf2f((ushort_t)(pk[c] & 0xffff)));
    run1 = fmaf(P[c], run1, bf2f((ushort_t)(pk[c] >> 16)));
    pk[c] = (uint32_t)f2bf(run0) | ((uint32_t)f2bf(run1) << 16);
  }
#pragma unroll
  for (int c = 0; c < NCH; c++) *(uint32_t*)(HSb + base + (size_t)c * 8192) = pk[c];
}

// ============================================================
// K5c: SSD output + GATE: v = (acc + D*x) * silu(z) -> y16 (bf16)
// ============================================================
__global__ __launch_bounds__(256) void k_ssd_y(const ushort_t* __restrict__ xcb,
    const ushort_t* __restrict__ zb,
    const float* __restrict__ dtb, const float* __restrict__ aw,
    const float* __restrict__ Dskip, const ushort_t* __restrict__ HSb,
    ushort_t* __restrict__ y16) {
  const int L = (blockIdx.x & 7) * 256 + (blockIdx.x >> 3);
  const int ch = L & 31, bh = L >> 5;
  const int b = bh >> 3, h = bh & 7;
  const int t0 = ch * QC;
  const int valid = (L_SEQ - t0 < QC) ? (L_SEQ - t0) : QC;
  const size_t rowbase = (size_t)b * L_SEQ;
  __shared__ __attribute__((aligned(16))) short sB[64][136];
  __shared__ __attribute__((aligned(16))) short sC[64][136];
  __shared__ __attribute__((aligned(16))) short sH[64][140];
  __shared__ __attribute__((aligned(16))) short sX[64][TP];
  __shared__ float sLrel[64], sdt[64], sEL[64];
  short (*sM)[72] = (short(*)[72])&sB[0][0];
  const int tid = threadIdx.x;
  if (tid < 64) {
    float aa = 0.f, dd = 0.f;
    if (tid < valid) { size_t r8 = (rowbase + t0 + tid) * 8 + h; aa = aw[r8]; dd = dtb[r8]; }
    float s = aa;
#pragma unroll
    for (int d = 1; d < 64; d <<= 1) { float o = __shfl_up(s, d, 64); if (tid >= d) s += o; }
    sLrel[tid] = s; sdt[tid] = dd; sEL[tid] = expf(s);
  }
  for (int i = tid; i < 64 * 16; i += 256) {
    int r = i >> 4, q = (i & 15) * 8;
    short8 vb = {0, 0, 0, 0, 0, 0, 0, 0}, vc = {0, 0, 0, 0, 0, 0, 0, 0};
    if (r < valid) {
      const ushort_t* rp = xcb + (rowbase + t0 + r) * CONV_DIM;
      vb = *(const short8*)(rp + 512 + q);
      vc = *(const short8*)(rp + 640 + q);
    }
    *(short8*)&sB[r][q] = vb;
    *(short8*)&sC[r][q] = vc;
  }
  for (int i = tid; i < 64 * 8; i += 256) {
    int r = i >> 3, q = (i & 7) * 8;
    short8 v = {0, 0, 0, 0, 0, 0, 0, 0};
    if (r < valid) v = *(const short8*)(xcb + (rowbase + t0 + r) * CONV_DIM + h * 64 + q);
#pragma unroll
    for (int j = 0; j < 8; j++) sX[q + j][r] = v[j];
  }
  for (int i = tid; i < 128 * 8; i += 256) {
    int n = i >> 3, q = (i & 7) * 8;
    short8 v = {0, 0, 0, 0, 0, 0, 0, 0};
    if (ch > 0) v = *(const short8*)(HSb + ((size_t)bh * NCH + (ch - 1)) * 8192 + n * 64 + q);
#pragma unroll
    for (int j = 0; j < 8; j++) sH[q + j][n] = v[j];
  }
  __syncthreads();
  const int w = tid >> 6, l15 = tid & 15, lK = (tid & 63) >> 4;
  short8 aC[4];
#pragma unroll
  for (int kt = 0; kt < 4; kt++)
    aC[kt] = *(const short8*)&sC[w * 16 + l15][kt * 32 + lK * 8];
  f32x4 g[4] = {};
#pragma unroll
  for (int st = 0; st < 4; st++)
#pragma unroll
    for (int kt = 0; kt < 4; kt++)
      g[st] = MFMA16(aC[kt], *(const short8*)&sB[st * 16 + l15][kt * 32 + lK * 8], g[st]);
  __syncthreads();
#pragma unroll
  for (int st = 0; st < 4; st++)
#pragma unroll
    for (int i = 0; i < 4; i++) {
      int tt = w * 16 + lK * 4 + i, ss = st * 16 + l15;
      float f = (ss <= tt) ? expf(sLrel[tt] - sLrel[ss]) * sdt[ss] : 0.f;
      sM[tt][ss] = (short)f2bf(g[st][i] * f);
    }
  __syncthreads();
  f32x4 acc[4] = {};
#pragma unroll
  for (int pt = 0; pt < 4; pt++)
#pragma unroll
    for (int kt = 0; kt < 4; kt++)
      acc[pt] = MFMA16(aC[kt], ld8(&sH[pt * 16 + l15][kt * 32 + lK * 8]), acc[pt]);
#pragma unroll
  for (int pt = 0; pt < 4; pt++)
#pragma unroll
    for (int i = 0; i < 4; i++)
      acc[pt][i] *= sEL[w * 16 + lK * 4 + i];
  short8 aM[2];
#pragma unroll
  for (int kt = 0; kt < 2; kt++)
    aM[kt] = *(const short8*)&sM[w * 16 + l15][kt * 32 + lK * 8];
#pragma unroll
  for (int pt = 0; pt < 4; pt++)
#pragma unroll
    for (int kt = 0; kt < 2; kt++)
      acc[pt] = MFMA16(aM[kt], ld8(&sX[pt * 16 + l15][kt * 32 + lK * 8]), acc[pt]);
  const float Dsk = Dskip[h];
#pragma unroll
  for (int pt = 0; pt < 4; pt++)
#pragma unroll
    for (int i = 0; i < 4; i++) {
      int tt = w * 16 + lK * 4 + i;
      int pp = pt * 16 + l15;
      float v = acc[pt][i] + Dsk * bf2f((ushort_t)sX[pp][tt]);
      // gate fused here (was k_norm's job): v *= silu(z)
      if (tt < valid) {
        float z = bf2f(zb[(rowbase + t0 + tt) * 512 + h * 64 + pp]);
        v *= siluf(z);
      }
      uint32_t mine = f2bf(v);
      uint32_t other = (uint32_t)__shfl_xor((int)mine, 1, 64);
      if (((l15 & 1) == 0) && tt < valid)
        *(uint32_t*)(y16 + (rowbase + t0 + tt) * D_INNER + h * 64 + pp) = mine | (other << 16);
    }
}

// ============================================================
// K6: k_scale — per-row RMSNorm scale only (no write-back of v).
// ============================================================
__global__ __launch_bounds__(256) void k_scale(const ushort_t* __restrict__ y16,
    float* __restrict__ scl) {
  const int row = blockIdx.x * 4 + (threadIdx.x >> 6);
  const int lane = threadIdx.x & 63;
  const int c0 = lane * 8;
  short8 yv = *(const short8*)(y16 + (size_t)row * D_INNER + c0);
  float ss = 0.f;
#pragma unroll
  for (int j = 0; j < 8; j++) {
    float v = bf2f((ushort_t)yv[j]);
    ss += v * v;
  }
#pragma unroll
  for (int m = 32; m >= 1; m >>= 1) ss += __shfl_xor(ss, m, 64);
  if (lane == 0)
    scl[row] = rsqrtf(ss * (1.f / 512.f) + 1e-5f);
}

// ============================================================
// K8: tail = diagonal gather-reduce + transposed conv (Yg bf16)
// ============================================================
__global__ __launch_bounds__(256) void k_tail(const ushort_t* __restrict__ Yg,
    const float* __restrict__ b1, const float* __restrict__ wT,
    const float* __restrict__ bT, float* __restrict__ out) {
  const int bid = blockIdx.x;
  const int sc = bid & 31, b = bid >> 5;
  const int s0 = sc * 512;
  const int mbase = (s0 - 15) >> 3;
  const int tid = threadIdx.x;
  __shared__ float sY[8][66];
  __shared__ float swT[8][4][16];
  __shared__ float sb1[8], sbT[4];
  for (int i = tid; i < 512; i += 256) {
    int j = i >> 6, c = (i >> 4) & 3, k = i & 15;
    swT[j][c][k] = wT[((size_t)j * 4 + c) * 16 + k];
  }
  if (tid < 8) sb1[tid] = b1[tid];
  if (tid < 4) sbT[tid] = bT[tid];
  __syncthreads();
  const ushort_t* Yb = Yg + (size_t)b * L_SEQ * 128;
  for (int item = tid; item < 8 * 66; item += 256) {
    int j = item / 66, ii = item % 66;
    int m = mbase + ii;
    float acc = 0.f;
    if ((unsigned)m < (unsigned)L_SEQ) {
      acc = sb1[j];
#pragma unroll
      for (int k = 0; k < 16; k++) {
        int tt = m - 7 + k;
        if ((unsigned)tt < (unsigned)L_SEQ) acc += bf2f(Yb[(size_t)tt * 128 + j * 16 + k]);
      }
    }
    sY[j][ii] = acc;
  }
  __syncthreads();
  const int c = tid >> 6, si = tid & 63;
  float ov[8];
#pragma unroll
  for (int u = 0; u < 8; u++) {
    int s = s0 + si * 8 + u;
    float acc = sbT[c];
    const int k0 = (15 - u) & 7;
#pragma unroll
    for (int dk = 0; dk < 2; dk++) {
      int k = k0 + 8 * dk;
      int num = s - 15 + k;
      int m = num >> 3;
      if (num >= 0 && m < L_SEQ) {
        int ii = m - mbase;
#pragma unroll
        for (int j = 0; j < 8; j++)
          acc = fmaf(sY[j][ii], swT[j][c][15 - k], acc);
      }
    }
    ov[u] = acc;
  }
  float* op = out + ((size_t)b * 4 + c) * L_IN + s0 + si * 8;
  *(float4*)op       = *(float4*)&ov[0];
  *(float4*)(op + 4) = *(float4*)&ov[4];
}

// ============================================================
extern "C" void kernel_launch(void* const* d_in, const int* in_sizes, int n_in,
                              void* d_out, int out_size, void* d_ws, size_t ws_size,
                              hipStream_t stream) {
  const float* x         = (const float*)d_in[0];
  const float* conv_w    = (const float*)d_in[1];
  const float* conv_b    = (const float*)d_in[2];
  const float* in_proj_w = (const float*)d_in[3];
  const float* conv1d_w  = (const float*)d_in[4];
  const float* conv1d_b  = (const float*)d_in[5];
  const float* dt_bias   = (const float*)d_in[6];
  const float* A_log     = (const float*)d_in[7];
  const float* D_skip    = (const float*)d_in[8];
  const float* norm_w    = (const float*)d_in[9];
  const float* out_proj_w= (const float*)d_in[10];
  const float* conv1_w   = (const float*)d_in[11];
  const float* conv1_b   = (const float*)d_in[12];
  const float* convT_w   = (const float*)d_in[13];
  const float* convT_b   = (const float*)d_in[14];
  float* out = (float*)d_out;
  float* ws  = (float*)d_ws;

  ushort_t* ub   = (ushort_t*)(ws + OFF_U);
  ushort_t* PB   = (ushort_t*)(ws + OFF_PB);
  ushort_t* zb   = (ushort_t*)(ws + OFF_ZB);
  ushort_t* xbcb = (ushort_t*)(ws + OFF_XBC);
  float* dtb  = ws + OFF_DT;
  float* awb  = ws + OFF_AW;
  ushort_t* xcb = (ushort_t*)(ws + OFF_XC);
  ushort_t* y16 = (ushort_t*)(ws + OFF_Y);
  float* scl  = ws + OFF_SCL;
  float* Pbuf = ws + OFF_PBUF;
  ushort_t* HSb = (ushort_t*)(ws + OFF_HS);
  ushort_t* wbin  = (ushort_t*)(ws + OFF_WBIN);
  ushort_t* wbf   = (ushort_t*)(ws + OFF_WBF);
  ushort_t* W2b   = (ushort_t*)(ws + OFF_W2);
  ushort_t* Ygb = (ushort_t*)(ws + OFF_U);  // Yg bf16; U region dead after in_proj

  // 0. merged prep: im2col + weight casts + W2 combine (x norm_w)
  k_prep<<<dim3(1928), 256, 0, stream>>>(x, in_proj_w, conv_w, conv1_w, out_proj_w,
                                         norm_w, PB, wbin, wbf, W2b);
  // 1. front conv GEMM (bias+relu+bf16 epilogue)
  gemm_bf16<1><<<dim3(256), 256, 0, stream>>>(PB, 64, wbf, 64, (float*)ub,
      conv_b, M_TOK, 256, 64, 2, nullptr, nullptr, nullptr, nullptr, nullptr, nullptr);
  // 2. in_proj GEMM, region-split epilogue (z->zb, xBC->xbcb, dt fused)
  gemm_bf16<2><<<dim3(1408), 256, 0, stream>>>(ub, 256, wbin, 256, nullptr,
      nullptr, M_TOK, D_IN_PROJ, 256, 11, zb, xbcb, dtb, awb, dt_bias, A_log);
  // 3. depthwise conv + silu -> xcb
  k_dw<<<dim3(BATCH * 512), 192, 0, stream>>>(xbcb, conv1d_w, conv1d_b, xcb);
  // 4. SSD scan (gate fused into ssd_y epilogue)
  k_ssd_state<<<dim3(2048), 256, 0, stream>>>(xcb, dtb, awb, HSb, Pbuf);
  k_ssd_comb<<<dim3(16, 64), 256, 0, stream>>>(HSb, Pbuf);
  k_ssd_y<<<dim3(2048), 256, 0, stream>>>(xcb, zb, dtb, awb, D_skip, HSb, y16);
  // 5. RMSNorm scale only (no v write-back)
  k_scale<<<dim3(M_TOK / 4), 256, 0, stream>>>(y16, scl);
  // 6. W2 GEMM with row-scale epilogue: Yg (bf16) = diag(scl) * v @ W2'^T
  gemm_bf16<3><<<dim3(128), 256, 0, stream>>>(y16, 512, W2b, 512, (float*)Ygb,
      scl, M_TOK, 128, D_INNER, 1, nullptr, nullptr, nullptr, nullptr, nullptr, nullptr);
  // 7. tail: gather-reduce + transposed conv -> out
  k_tail<<<dim3(256), 256, 0, stream>>>(Ygb, conv1_b, convT_w, convT_b, out);
}

// Round 21
// 188.635 us; speedup vs baseline: 1.0698x; 1.0698x over previous
//
#include <hip/hip_runtime.h>
#include <cstddef>
#include <cstdint>

// ---------------- problem constants ----------------
constexpr int L_IN   = 16384;
constexpr int L_SEQ  = 2047;          // (16384-16)/8 + 1
constexpr int BATCH  = 8;
constexpr int M_TOK  = BATCH * L_SEQ; // 16376
constexpr int D_INNER = 512;
constexpr int NHEADS  = 8;
constexpr int HEADDIM = 64;
constexpr int D_STATE = 128;
constexpr int CONV_DIM = 768;
constexpr int D_IN_PROJ = 1288;

// SSD chunking
constexpr int QC  = 64;
constexpr int NCH = 32;

// padded stride for transposed LDS tiles: 84 shorts = 168B = 42 dwords.
constexpr int TP = 84;

// ---------------- workspace layout (float slots) ----------------
constexpr size_t OFF_U    = 0;                       // ub bf16 / later Yg bf16
constexpr size_t OFF_PB   = OFF_U   + 2096128;       // im2col bf16
constexpr size_t OFF_ZB   = OFF_U   + 4192256;       // z bf16 [row][512]
constexpr size_t OFF_XBC  = OFF_ZB  + 4192256;       // xBC bf16 [row][768]
constexpr size_t OFF_DT   = OFF_XBC + 6288384;       // dt fp32 [row][8]
constexpr size_t OFF_AW   = OFF_DT  + 131008;        // aw fp32
constexpr size_t OFF_XC   = OFF_AW  + 131008;        // xc bf16 [row][768]
constexpr size_t OFF_Y    = OFF_XC  + 6288384;       // y bf16 [row][512]
constexpr size_t OFF_YC1  = OFF_Y   + 4192256;       // (unused / OOB slack)
constexpr size_t OFF_PBUF = OFF_YC1 + 131008;        // Pbuf fp32
constexpr size_t OFF_HS   = OFF_PBUF + 2048;         // HS bf16
constexpr size_t OFF_WBIN = OFF_HS  + 8388608;
constexpr size_t OFF_WBF  = OFF_WBIN + 164864;
constexpr size_t OFF_W2   = OFF_WBF + 8192;
// OOB-read audit: unchanged from R10 (unguarded over-reads inside ws, finite;
// affected acc rows store-guarded).

using short8 = __attribute__((ext_vector_type(8))) short;  // 8 bf16
using short4v = __attribute__((ext_vector_type(4))) short;
using f32x4  = __attribute__((ext_vector_type(4))) float;
typedef unsigned short ushort_t;

__device__ __forceinline__ ushort_t f2bf(float f) {        // RNE f32->bf16
  uint32_t u = __float_as_uint(f);
  u += 0x7fffu + ((u >> 16) & 1u);
  return (ushort_t)(u >> 16);
}
__device__ __forceinline__ float bf2f(ushort_t h) {
  return __uint_as_float(((uint32_t)h) << 16);
}
__device__ __forceinline__ float siluf(float a) { return a / (1.f + expf(-a)); }
// 8B-aligned short8 load (two b64 reads) for TP-padded LDS rows
__device__ __forceinline__ short8 ld8(const short* p) {
  short4v a = *(const short4v*)p;
  short4v b = *(const short4v*)(p + 4);
  short8 r;
  r[0] = a[0]; r[1] = a[1]; r[2] = a[2]; r[3] = a[3];
  r[4] = b[0]; r[5] = b[1]; r[6] = b[2]; r[7] = b[3];
  return r;
}
#define MFMA16(a, b, c) __builtin_amdgcn_mfma_f32_16x16x32_bf16(a, b, c, 0, 0, 0)

#define GLD_LDS(gp, lp) __builtin_amdgcn_global_load_lds( \
    (const __attribute__((address_space(1))) void*)(gp),  \
    (__attribute__((address_space(3))) void*)(lp), 16, 0, 0)

// ============================================================
// K_prep: merged {im2col | weight casts | W2 combine}
// ============================================================
__global__ __launch_bounds__(256) void k_prep(const float* __restrict__ x,
    const float* __restrict__ w1, const float* __restrict__ w3,
    const float* __restrict__ conv1_w, const float* __restrict__ wout,
    ushort_t* __restrict__ PB, ushort_t* __restrict__ o1, ushort_t* __restrict__ o3,
    ushort_t* __restrict__ W2b) {
  const int bid = blockIdx.x;
  const int tid = threadIdx.x;
  if (bid < 512) {
    int idx = bid * 256 + tid;
    if (idx >= M_TOK * 8) return;
    int oct = idx & 7, row = idx >> 3;
    int t = row % L_SEQ, b = row / L_SEQ;
    int ic = oct >> 1, k0 = (oct & 1) * 8;
    const float* src = x + ((size_t)b * 4 + ic) * L_IN + t * 8 + k0;
    float4 a0 = *(const float4*)src;
    float4 a1 = *(const float4*)(src + 4);
    short8 o;
    o[0] = (short)f2bf(a0.x); o[1] = (short)f2bf(a0.y);
    o[2] = (short)f2bf(a0.z); o[3] = (short)f2bf(a0.w);
    o[4] = (short)f2bf(a1.x); o[5] = (short)f2bf(a1.y);
    o[6] = (short)f2bf(a1.z); o[7] = (short)f2bf(a1.w);
    *(short8*)(PB + (size_t)row * 64 + oct * 8) = o;
  } else if (bid < 1800) {
    int i = (bid - 512) * 256 + tid;
    if (i < D_IN_PROJ * 256) o1[i] = f2bf(w1[i]);
    if (i < 256 * 64)        o3[i] = f2bf(w3[i]);
  } else {
    const int r = bid - 1800;          // 0..127
    const int oc = r >> 4, k = r & 15;
    const int d0 = tid;
    float acc0 = 0.f, acc1 = 0.f;
    for (int o = 0; o < 256; o++) {
      float wv = conv1_w[((size_t)oc * 256 + o) * 16 + k];
      acc0 = fmaf(wv, wout[(size_t)o * 512 + d0], acc0);
      acc1 = fmaf(wv, wout[(size_t)o * 512 + d0 + 256], acc1);
    }
    W2b[(size_t)r * 512 + d0]       = f2bf(acc0);
    W2b[(size_t)r * 512 + d0 + 256] = f2bf(acc1);
  }
}

// ============================================================
// K2: bf16 MFMA GEMM NT — 2-phase dbuf global_load_lds staging.
// EPI=1: +bias+relu bf16 store.  EPI=2: in_proj region-split.
// EPI=3: plain bf16 packed-pair store (W2 GEMM -> Yg bf16).
// ============================================================
template<int EPI>
__global__ __launch_bounds__(256) void gemm_bf16(const ushort_t* __restrict__ A, int lda,
    const ushort_t* __restrict__ B, int ldb, float* __restrict__ C,
    const float* __restrict__ bias, int M, int N, int K, int nx,
    ushort_t* __restrict__ zb, ushort_t* __restrict__ xbcb,
    float* __restrict__ dtb, float* __restrict__ awb,
    const float* __restrict__ dt_bias, const float* __restrict__ A_log) {
  __shared__ __attribute__((aligned(16))) ushort_t sA[2][128 * 64];
  __shared__ __attribute__((aligned(16))) ushort_t sB[2][128 * 64];
  const int tid = threadIdx.x;
  const int cpx = gridDim.x >> 3;
  const int swz = (blockIdx.x & 7) * cpx + (blockIdx.x >> 3);
  const int m0 = (swz / nx) * 128, n0 = (swz % nx) * 128;
  const int w = tid >> 6, lane = tid & 63;
  const int l15 = lane & 15, lK = lane >> 4;
  const int wr = w >> 1, wc = w & 1;
  f32x4 acc[4][4] = {};

  auto STAGE = [&](int buf, int k0) {
#pragma unroll
    for (int j = 0; j < 4; j++) {
      int idx = j * 256 + tid;
      int r = idx >> 3;
      int ss = (idx & 7) ^ (r & 7);
      GLD_LDS(A + (size_t)(m0 + r) * lda + k0 + ss * 8, &sA[buf][(j * 256 + w * 64) * 8]);
      GLD_LDS(B + (size_t)(n0 + r) * ldb + k0 + ss * 8, &sB[buf][(j * 256 + w * 64) * 8]);
    }
  };

  STAGE(0, 0);
  __syncthreads();
  int cur = 0;
  for (int k0 = 0; k0 < K; k0 += 64) {
    if (k0 + 64 < K) STAGE(cur ^ 1, k0 + 64);
#pragma unroll
    for (int kk = 0; kk < 2; kk++) {
      short8 af[4], bf[4];
#pragma unroll
      for (int mt = 0; mt < 4; mt++) {
        int r = wr * 64 + mt * 16 + l15;
        af[mt] = *(const short8*)&sA[cur][r * 64 + (((kk * 4 + lK) ^ (r & 7)) * 8)];
      }
#pragma unroll
      for (int nt = 0; nt < 4; nt++) {
        int r = wc * 64 + nt * 16 + l15;
        bf[nt] = *(const short8*)&sB[cur][r * 64 + (((kk * 4 + lK) ^ (r & 7)) * 8)];
      }
#pragma unroll
      for (int mt = 0; mt < 4; mt++)
#pragma unroll
        for (int nt = 0; nt < 4; nt++)
          acc[mt][nt] = MFMA16(af[mt], bf[nt], acc[mt][nt]);
    }
    __syncthreads();
    cur ^= 1;
  }
  if constexpr (EPI == 1) {
    ushort_t* Cb = (ushort_t*)C;
#pragma unroll
    for (int mt = 0; mt < 4; mt++)
#pragma unroll
      for (int i = 0; i < 4; i++) {
        int gm = m0 + wr * 64 + mt * 16 + lK * 4 + i;
#pragma unroll
        for (int nt = 0; nt < 4; nt++) {
          int gn = n0 + wc * 64 + nt * 16 + l15;
          float v = fmaxf(acc[mt][nt][i] + bias[gn], 0.f);
          uint32_t mine = f2bf(v);
          uint32_t other = (uint32_t)__shfl_xor((int)mine, 1, 64);
          if (((lane & 1) == 0) && gm < M)
            *(uint32_t*)(Cb + (size_t)gm * N + gn) = mine | (other << 16);
        }
      }
  } else if constexpr (EPI == 3) {
    ushort_t* Cb = (ushort_t*)C;
#pragma unroll
    for (int mt = 0; mt < 4; mt++)
#pragma unroll
      for (int i = 0; i < 4; i++) {
        int gm = m0 + wr * 64 + mt * 16 + lK * 4 + i;
#pragma unroll
        for (int nt = 0; nt < 4; nt++) {
          int gn = n0 + wc * 64 + nt * 16 + l15;
          uint32_t mine = f2bf(acc[mt][nt][i]);
          uint32_t other = (uint32_t)__shfl_xor((int)mine, 1, 64);
          if (((lane & 1) == 0) && gm < M)
            *(uint32_t*)(Cb + (size_t)gm * N + gn) = mine | (other << 16);
        }
      }
  } else {
    if (n0 < 1280) {
      ushort_t* dst = (n0 < 512) ? zb : xbcb;
      const int ldd  = (n0 < 512) ? 512 : 768;
      const int coff = (n0 < 512) ? 0 : 512;
#pragma unroll
      for (int mt = 0; mt < 4; mt++)
#pragma unroll
        for (int i = 0; i < 4; i++) {
          int gm = m0 + wr * 64 + mt * 16 + lK * 4 + i;
#pragma unroll
          for (int nt = 0; nt < 4; nt++) {
            int gn = n0 + wc * 64 + nt * 16 + l15;
            uint32_t mine = f2bf(acc[mt][nt][i]);
            uint32_t other = (uint32_t)__shfl_xor((int)mine, 1, 64);
            if (((lane & 1) == 0) && gm < M)
              *(uint32_t*)(dst + (size_t)gm * ldd + (gn - coff)) = mine | (other << 16);
          }
        }
    } else {
#pragma unroll
      for (int mt = 0; mt < 4; mt++)
#pragma unroll
        for (int i = 0; i < 4; i++) {
          int gm = m0 + wr * 64 + mt * 16 + lK * 4 + i;
          if (gm >= M) continue;
#pragma unroll
          for (int nt = 0; nt < 4; nt++) {
            int gn = n0 + wc * 64 + nt * 16 + l15;
            if (gn < N) {
              int hd = gn - 1280;
              float v = acc[mt][nt][i] + dt_bias[hd];
              float sp = (v > 20.f) ? v : log1pf(expf(v));
              dtb[(size_t)gm * 8 + hd] = sp;
              awb[(size_t)gm * 8 + hd] = -expf(A_log[hd]) * sp;
            }
          }
        }
    }
  }
}

// ============================================================
// K4: depthwise causal conv + bias + silu, t-blocked sliding window.
// ============================================================
__global__ __launch_bounds__(192) void k_dw(const ushort_t* __restrict__ xbcb,
    const float* __restrict__ w, const float* __restrict__ bias,
    ushort_t* __restrict__ xcb) {
  const int bid = blockIdx.x;          // b*512 + tb
  const int tb = bid & 511, b = bid >> 9;
  const int t0 = tb * 4;
  const int c = threadIdx.x * 4;
  const size_t rowb = (size_t)b * L_SEQ;
  float wr[4][4];
#pragma unroll
  for (int j = 0; j < 4; j++)
#pragma unroll
    for (int k = 0; k < 4; k++) wr[j][k] = w[(c + j) * 4 + k];
  const float4 bs = {bias[c], bias[c + 1], bias[c + 2], bias[c + 3]};
  float v[7][4];
#pragma unroll
  for (int r = 0; r < 7; r++) {
    int tt = t0 - 3 + r;
    if (tt >= 0 && tt < L_SEQ) {
      uint2 pk = *(const uint2*)(xbcb + (rowb + tt) * CONV_DIM + c);
      v[r][0] = bf2f((ushort_t)(pk.x & 0xffff));
      v[r][1] = bf2f((ushort_t)(pk.x >> 16));
      v[r][2] = bf2f((ushort_t)(pk.y & 0xffff));
      v[r][3] = bf2f((ushort_t)(pk.y >> 16));
    } else {
      v[r][0] = v[r][1] = v[r][2] = v[r][3] = 0.f;
    }
  }
#pragma unroll
  for (int o = 0; o < 4; o++) {
    int t = t0 + o;
    if (t >= L_SEQ) break;
    float a0 = bs.x, a1 = bs.y, a2 = bs.z, a3 = bs.w;
#pragma unroll
    for (int k = 0; k < 4; k++) {
      a0 = fmaf(v[o + k][0], wr[0][k], a0);
      a1 = fmaf(v[o + k][1], wr[1][k], a1);
      a2 = fmaf(v[o + k][2], wr[2][k], a2);
      a3 = fmaf(v[o + k][3], wr[3][k], a3);
    }
    uint2 ov;
    ov.x = (uint32_t)f2bf(siluf(a0)) | ((uint32_t)f2bf(siluf(a1)) << 16);
    ov.y = (uint32_t)f2bf(siluf(a2)) | ((uint32_t)f2bf(siluf(a3)) << 16);
    *(uint2*)(xcb + (rowb + t) * CONV_DIM + c) = ov;
  }
}

// ============================================================
// K5a: SSD chunk states (TP-padded transpose tiles; chunked XCD swizzle)
// ============================================================
__global__ __launch_bounds__(256) void k_ssd_state(const ushort_t* __restrict__ xcb,
    const float* __restrict__ dtb, const float* __restrict__ aw,
    ushort_t* __restrict__ HSb, float* __restrict__ Pbuf) {
  const int L = (blockIdx.x & 7) * 256 + (blockIdx.x >> 3);   // bijective, 2048%8==0
  const int ch = L & 31, bh = L >> 5;
  const int b = bh >> 3, h = bh & 7;
  const int t0 = ch * QC;
  const int valid = (L_SEQ - t0 < QC) ? (L_SEQ - t0) : QC;
  const size_t rowbase = (size_t)b * L_SEQ;
  __shared__ __attribute__((aligned(16))) short sBT[128][TP];
  __shared__ __attribute__((aligned(16))) short sXw[64][TP];
  __shared__ float sW[64];
  __shared__ float sLtot;
  const int tid = threadIdx.x;
  if (tid < 64) {
    float aa = 0.f, dd = 0.f;
    if (tid < valid) { size_t r8 = (rowbase + t0 + tid) * 8 + h; aa = aw[r8]; dd = dtb[r8]; }
    float s = aa;
#pragma unroll
    for (int d = 1; d < 64; d <<= 1) { float o = __shfl_up(s, d, 64); if (tid >= d) s += o; }
    float Lt = __shfl(s, 63, 64);
    sW[tid] = expf(Lt - s) * dd;
    if (tid == 63) sLtot = s;
  }
  __syncthreads();
  for (int i = tid; i < 64 * 16; i += 256) {
    int r = i >> 4, q = (i & 15) * 8;
    short8 v = {0, 0, 0, 0, 0, 0, 0, 0};
    if (r < valid) v = *(const short8*)(xcb + (rowbase + t0 + r) * CONV_DIM + 512 + q);
#pragma unroll
    for (int j = 0; j < 8; j++) sBT[q + j][r] = v[j];
  }
  for (int i = tid; i < 64 * 8; i += 256) {
    int r = i >> 3, q = (i & 7) * 8;
    short8 v = {0, 0, 0, 0, 0, 0, 0, 0};
    if (r < valid) v = *(const short8*)(xcb + (rowbase + t0 + r) * CONV_DIM + h * 64 + q);
    float wv = sW[r];
#pragma unroll
    for (int j = 0; j < 8; j++) sXw[q + j][r] = (short)f2bf(bf2f((ushort_t)v[j]) * wv);
  }
  __syncthreads();
  const int w = tid >> 6, l15 = tid & 15, lK = (tid & 63) >> 4;
  f32x4 acc[2][4] = {};
  short8 afr[2][2];
#pragma unroll
  for (int j = 0; j < 2; j++)
#pragma unroll
    for (int kt = 0; kt < 2; kt++)
      afr[j][kt] = ld8(&sBT[(w * 2 + j) * 16 + l15][kt * 32 + lK * 8]);
#pragma unroll
  for (int pt = 0; pt < 4; pt++) {
#pragma unroll
    for (int kt = 0; kt < 2; kt++) {
      short8 bfr = ld8(&sXw[pt * 16 + l15][kt * 32 + lK * 8]);
      acc[0][pt] = MFMA16(afr[0][kt], bfr, acc[0][pt]);
      acc[1][pt] = MFMA16(afr[1][kt], bfr, acc[1][pt]);
    }
  }
  ushort_t* dst = HSb + ((size_t)bh * NCH + ch) * 8192;
#pragma unroll
  for (int j = 0; j < 2; j++)
#pragma unroll
    for (int pt = 0; pt < 4; pt++)
#pragma unroll
      for (int i = 0; i < 4; i++) {
        int n = (w * 2 + j) * 16 + lK * 4 + i, p = pt * 16 + l15;
        uint32_t mine = f2bf(acc[j][pt][i]);
        uint32_t other = (uint32_t)__shfl_xor((int)mine, 1, 64);
        if ((l15 & 1) == 0)
          *(uint32_t*)(dst + n * 64 + p) = mine | (other << 16);
      }
  if (tid == 0) Pbuf[bh * NCH + ch] = expf(sLtot);
}

// ============================================================
// K5b: inter-chunk combine (batch reg load, fp32 chain, batch store)
// ============================================================
__global__ __launch_bounds__(256) void k_ssd_comb(ushort_t* __restrict__ HSb,
                                                  const float* __restrict__ Pbuf) {
  const int bh = blockIdx.y;
  const int e2 = blockIdx.x * 256 + threadIdx.x;
  const size_t base = (size_t)bh * NCH * 8192 + (size_t)e2 * 2;
  uint32_t pk[NCH];
  float P[NCH];
#pragma unroll
  for (int c = 0; c < NCH; c++) pk[c] = *(const uint32_t*)(HSb + base + (size_t)c * 8192);
#pragma unroll
  for (int c = 0; c < NCH; c++) P[c] = Pbuf[bh * NCH + c];
  float run0 = 0.f, run1 = 0.f;
#pragma unroll
  for (int c = 0; c < NCH; c++) {
    run0 = fmaf(P[c], run0, bf2f((ushort_t)(pk[c] & 0xffff)));
    run1 = fmaf(P[c], run1, bf2f((ushort_t)(pk[c] >> 16)));
    pk[c] = (uint32_t)f2bf(run0) | ((uint32_t)f2bf(run1) << 16);
  }
#pragma unroll
  for (int c = 0; c < NCH; c++) *(uint32_t*)(HSb + base + (size_t)c * 8192) = pk[c];
}

// ============================================================
// K5c: SSD output (TP-padded sX/sH; b128 sB/sC stores; XCD swizzle) -> y bf16
// ============================================================
__global__ __launch_bounds__(256) void k_ssd_y(const ushort_t* __restrict__ xcb,
    const float* __restrict__ dtb, const float* __restrict__ aw,
    const float* __restrict__ Dskip, const ushort_t* __restrict__ HSb,
    ushort_t* __restrict__ y16) {
  const int L = (blockIdx.x & 7) * 256 + (blockIdx.x >> 3);
  const int ch = L & 31, bh = L >> 5;
  const int b = bh >> 3, h = bh & 7;
  const int t0 = ch * QC;
  const int valid = (L_SEQ - t0 < QC) ? (L_SEQ - t0) : QC;
  const size_t rowbase = (size_t)b * L_SEQ;
  __shared__ __attribute__((aligned(16))) short sB[64][136];
  __shared__ __attribute__((aligned(16))) short sC[64][136];
  __shared__ __attribute__((aligned(16))) short sH[64][140];
  __shared__ __attribute__((aligned(16))) short sX[64][TP];
  __shared__ float sLrel[64], sdt[64], sEL[64];
  short (*sM)[72] = (short(*)[72])&sB[0][0];   // alias (rows 72 = 144B)
  const int tid = threadIdx.x;
  if (tid < 64) {
    float aa = 0.f, dd = 0.f;
    if (tid < valid) { size_t r8 = (rowbase + t0 + tid) * 8 + h; aa = aw[r8]; dd = dtb[r8]; }
    float s = aa;
#pragma unroll
    for (int d = 1; d < 64; d <<= 1) { float o = __shfl_up(s, d, 64); if (tid >= d) s += o; }
    sLrel[tid] = s; sdt[tid] = dd; sEL[tid] = expf(s);
  }
  for (int i = tid; i < 64 * 16; i += 256) {
    int r = i >> 4, q = (i & 15) * 8;
    short8 vb = {0, 0, 0, 0, 0, 0, 0, 0}, vc = {0, 0, 0, 0, 0, 0, 0, 0};
    if (r < valid) {
      const ushort_t* rp = xcb + (rowbase + t0 + r) * CONV_DIM;
      vb = *(const short8*)(rp + 512 + q);
      vc = *(const short8*)(rp + 640 + q);
    }
    *(short8*)&sB[r][q] = vb;            // direct copy: single ds_write_b128
    *(short8*)&sC[r][q] = vc;
  }
  for (int i = tid; i < 64 * 8; i += 256) {
    int r = i >> 3, q = (i & 7) * 8;
    short8 v = {0, 0, 0, 0, 0, 0, 0, 0};
    if (r < valid) v = *(const short8*)(xcb + (rowbase + t0 + r) * CONV_DIM + h * 64 + q);
#pragma unroll
    for (int j = 0; j < 8; j++) sX[q + j][r] = v[j];
  }
  for (int i = tid; i < 128 * 8; i += 256) {
    int n = i >> 3, q = (i & 7) * 8;
    short8 v = {0, 0, 0, 0, 0, 0, 0, 0};
    if (ch > 0) v = *(const short8*)(HSb + ((size_t)bh * NCH + (ch - 1)) * 8192 + n * 64 + q);
#pragma unroll
    for (int j = 0; j < 8; j++) sH[q + j][n] = v[j];
  }
  __syncthreads();
  const int w = tid >> 6, l15 = tid & 15, lK = (tid & 63) >> 4;
  short8 aC[4];
#pragma unroll
  for (int kt = 0; kt < 4; kt++)
    aC[kt] = *(const short8*)&sC[w * 16 + l15][kt * 32 + lK * 8];
  f32x4 g[4] = {};
#pragma unroll
  for (int st = 0; st < 4; st++)
#pragma unroll
    for (int kt = 0; kt < 4; kt++)
      g[st] = MFMA16(aC[kt], *(const short8*)&sB[st * 16 + l15][kt * 32 + lK * 8], g[st]);
  __syncthreads();
#pragma unroll
  for (int st = 0; st < 4; st++)
#pragma unroll
    for (int i = 0; i < 4; i++) {
      int tt = w * 16 + lK * 4 + i, ss = st * 16 + l15;
      float f = (ss <= tt) ? expf(sLrel[tt] - sLrel[ss]) * sdt[ss] : 0.f;
      sM[tt][ss] = (short)f2bf(g[st][i] * f);
    }
  __syncthreads();
  f32x4 acc[4] = {};
#pragma unroll
  for (int pt = 0; pt < 4; pt++)
#pragma unroll
    for (int kt = 0; kt < 4; kt++)
      acc[pt] = MFMA16(aC[kt], ld8(&sH[pt * 16 + l15][kt * 32 + lK * 8]), acc[pt]);
#pragma unroll
  for (int pt = 0; pt < 4; pt++)
#pragma unroll
    for (int i = 0; i < 4; i++)
      acc[pt][i] *= sEL[w * 16 + lK * 4 + i];
  short8 aM[2];
#pragma unroll
  for (int kt = 0; kt < 2; kt++)
    aM[kt] = *(const short8*)&sM[w * 16 + l15][kt * 32 + lK * 8];
#pragma unroll
  for (int pt = 0; pt < 4; pt++)
#pragma unroll
    for (int kt = 0; kt < 2; kt++)
      acc[pt] = MFMA16(aM[kt], ld8(&sX[pt * 16 + l15][kt * 32 + lK * 8]), acc[pt]);
  const float Dsk = Dskip[h];
#pragma unroll
  for (int pt = 0; pt < 4; pt++)
#pragma unroll
    for (int i = 0; i < 4; i++) {
      int tt = w * 16 + lK * 4 + i;
      int pp = pt * 16 + l15;
      float v = acc[pt][i] + Dsk * bf2f((ushort_t)sX[pp][tt]);
      uint32_t mine = f2bf(v);
      uint32_t other = (uint32_t)__shfl_xor((int)mine, 1, 64);
      if (((l15 & 1) == 0) && tt < valid)
        *(uint32_t*)(y16 + (rowbase + t0 + tt) * D_INNER + h * 64 + pp) = mine | (other << 16);
    }
}

// ============================================================
// K6: gate + RMSNorm, wave-per-row (64 lanes x 8 ch), short8 16B I/O
// ============================================================
__global__ __launch_bounds__(256) void k_norm(ushort_t* __restrict__ y16,
    const ushort_t* __restrict__ zb, const float* __restrict__ norm_w) {
  const int row = blockIdx.x * 4 + (threadIdx.x >> 6);
  const int lane = threadIdx.x & 63;
  const int c0 = lane * 8;
  ushort_t* yrow = y16 + (size_t)row * D_INNER;
  short8 yv = *(const short8*)(yrow + c0);
  short8 zv = *(const short8*)(zb + (size_t)row * 512 + c0);
  float v[8];
  float ss = 0.f;
#pragma unroll
  for (int j = 0; j < 8; j++) {
    float z = bf2f((ushort_t)zv[j]);
    float g = z / (1.f + expf(-z));
    v[j] = bf2f((ushort_t)yv[j]) * g;
    ss += v[j] * v[j];
  }
#pragma unroll
  for (int m = 32; m >= 1; m >>= 1) ss += __shfl_xor(ss, m, 64);
  float scale = rsqrtf(ss * (1.f / 512.f) + 1e-5f);
  float4 nw0 = *(const float4*)(norm_w + c0);
  float4 nw1 = *(const float4*)(norm_w + c0 + 4);
  short8 o;
  o[0] = (short)f2bf(v[0] * scale * nw0.x); o[1] = (short)f2bf(v[1] * scale * nw0.y);
  o[2] = (short)f2bf(v[2] * scale * nw0.z); o[3] = (short)f2bf(v[3] * scale * nw0.w);
  o[4] = (short)f2bf(v[4] * scale * nw1.x); o[5] = (short)f2bf(v[5] * scale * nw1.y);
  o[6] = (short)f2bf(v[6] * scale * nw1.z); o[7] = (short)f2bf(v[7] * scale * nw1.w);
  *(short8*)(yrow + c0) = o;
}

// ============================================================
// K8: tail = diagonal gather-reduce + transposed conv (Yg bf16)
// ============================================================
__global__ __launch_bounds__(256) void k_tail(const ushort_t* __restrict__ Yg,
    const float* __restrict__ b1, const float* __restrict__ wT,
    const float* __restrict__ bT, float* __restrict__ out) {
  const int bid = blockIdx.x;
  const int sc = bid & 31, b = bid >> 5;
  const int s0 = sc * 512;
  const int mbase = (s0 - 15) >> 3;
  const int tid = threadIdx.x;
  __shared__ float sY[8][66];
  __shared__ float swT[8][4][16];
  __shared__ float sb1[8], sbT[4];
  for (int i = tid; i < 512; i += 256) {
    int j = i >> 6, c = (i >> 4) & 3, k = i & 15;
    swT[j][c][k] = wT[((size_t)j * 4 + c) * 16 + k];
  }
  if (tid < 8) sb1[tid] = b1[tid];
  if (tid < 4) sbT[tid] = bT[tid];
  __syncthreads();
  const ushort_t* Yb = Yg + (size_t)b * L_SEQ * 128;
  for (int item = tid; item < 8 * 66; item += 256) {
    int j = item / 66, ii = item % 66;
    int m = mbase + ii;
    float acc = 0.f;
    if ((unsigned)m < (unsigned)L_SEQ) {
      acc = sb1[j];
#pragma unroll
      for (int k = 0; k < 16; k++) {
        int tt = m - 7 + k;
        if ((unsigned)tt < (unsigned)L_SEQ) acc += bf2f(Yb[(size_t)tt * 128 + j * 16 + k]);
      }
    }
    sY[j][ii] = acc;
  }
  __syncthreads();
  const int c = tid >> 6, si = tid & 63;
  float ov[8];
#pragma unroll
  for (int u = 0; u < 8; u++) {
    int s = s0 + si * 8 + u;
    float acc = sbT[c];
    const int k0 = (15 - u) & 7;
#pragma unroll
    for (int dk = 0; dk < 2; dk++) {
      int k = k0 + 8 * dk;
      int num = s - 15 + k;
      int m = num >> 3;
      if (num >= 0 && m < L_SEQ) {
        int ii = m - mbase;
#pragma unroll
        for (int j = 0; j < 8; j++)
          acc = fmaf(sY[j][ii], swT[j][c][15 - k], acc);
      }
    }
    ov[u] = acc;
  }
  float* op = out + ((size_t)b * 4 + c) * L_IN + s0 + si * 8;
  *(float4*)op       = *(float4*)&ov[0];
  *(float4*)(op + 4) = *(float4*)&ov[4];
}

// ============================================================
extern "C" void kernel_launch(void* const* d_in, const int* in_sizes, int n_in,
                              void* d_out, int out_size, void* d_ws, size_t ws_size,
                              hipStream_t stream) {
  const float* x         = (const float*)d_in[0];
  const float* conv_w    = (const float*)d_in[1];
  const float* conv_b    = (const float*)d_in[2];
  const float* in_proj_w = (const float*)d_in[3];
  const float* conv1d_w  = (const float*)d_in[4];
  const float* conv1d_b  = (const float*)d_in[5];
  const float* dt_bias   = (const float*)d_in[6];
  const float* A_log     = (const float*)d_in[7];
  const float* D_skip    = (const float*)d_in[8];
  const float* norm_w    = (const float*)d_in[9];
  const float* out_proj_w= (const float*)d_in[10];
  const float* conv1_w   = (const float*)d_in[11];
  const float* conv1_b   = (const float*)d_in[12];
  const float* convT_w   = (const float*)d_in[13];
  const float* convT_b   = (const float*)d_in[14];
  float* out = (float*)d_out;
  float* ws  = (float*)d_ws;

  ushort_t* ub   = (ushort_t*)(ws + OFF_U);
  ushort_t* PB   = (ushort_t*)(ws + OFF_PB);
  ushort_t* zb   = (ushort_t*)(ws + OFF_ZB);
  ushort_t* xbcb = (ushort_t*)(ws + OFF_XBC);
  float* dtb  = ws + OFF_DT;
  float* awb  = ws + OFF_AW;
  ushort_t* xcb = (ushort_t*)(ws + OFF_XC);
  ushort_t* y16 = (ushort_t*)(ws + OFF_Y);
  float* Pbuf = ws + OFF_PBUF;
  ushort_t* HSb = (ushort_t*)(ws + OFF_HS);
  ushort_t* wbin  = (ushort_t*)(ws + OFF_WBIN);
  ushort_t* wbf   = (ushort_t*)(ws + OFF_WBF);
  ushort_t* W2b   = (ushort_t*)(ws + OFF_W2);
  ushort_t* Ygb = (ushort_t*)(ws + OFF_U);  // Yg bf16; U region dead after in_proj

  // 0. merged prep: im2col + weight casts + W2 combine
  k_prep<<<dim3(1928), 256, 0, stream>>>(x, in_proj_w, conv_w, conv1_w, out_proj_w,
                                         PB, wbin, wbf, W2b);
  // 1. front conv GEMM (bias+relu+bf16 epilogue)
  gemm_bf16<1><<<dim3(256), 256, 0, stream>>>(PB, 64, wbf, 64, (float*)ub,
      conv_b, M_TOK, 256, 64, 2, nullptr, nullptr, nullptr, nullptr, nullptr, nullptr);
  // 2. in_proj GEMM, region-split epilogue (z->zb, xBC->xbcb, dt fused)
  gemm_bf16<2><<<dim3(1408), 256, 0, stream>>>(ub, 256, wbin, 256, nullptr,
      nullptr, M_TOK, D_IN_PROJ, 256, 11, zb, xbcb, dtb, awb, dt_bias, A_log);
  // 3. depthwise conv + silu -> xcb
  k_dw<<<dim3(BATCH * 512), 192, 0, stream>>>(xbcb, conv1d_w, conv1d_b, xcb);
  // 4. SSD scan (1D grids, chunked XCD swizzle)
  k_ssd_state<<<dim3(2048), 256, 0, stream>>>(xcb, dtb, awb, HSb, Pbuf);
  k_ssd_comb<<<dim3(16, 64), 256, 0, stream>>>(HSb, Pbuf);
  k_ssd_y<<<dim3(2048), 256, 0, stream>>>(xcb, dtb, awb, D_skip, HSb, y16);
  // 5. gate + RMSNorm (wave-per-row, bf16 in place)
  k_norm<<<dim3(M_TOK / 4), 256, 0, stream>>>(y16, zb, norm_w);
  // 6. combined out_proj+conv1 GEMM: Yg (bf16) = ynorm @ W2^T
  gemm_bf16<3><<<dim3(128), 256, 0, stream>>>(y16, 512, W2b, 512, (float*)Ygb,
      nullptr, M_TOK, 128, D_INNER, 1, nullptr, nullptr, nullptr, nullptr, nullptr, nullptr);
  // 7. tail: gather-reduce + transposed conv -> out
  k_tail<<<dim3(256), 256, 0, stream>>>(Ygb, conv1_b, convT_w, convT_b, out);
}